// Round 6
// baseline (326.115 us; speedup 1.0000x reference)
//
#include <hip/hip_runtime.h>
#include <hip/hip_bf16.h>

// Problem constants (B=4, S=4096, D=1024)
#define BB 4
#define SS 4096
#define DD 1024
#define MM (BB * SS)   // 16384 rows
#define KK DD          // 1024  reduction dim
#define NN (4 * DD)    // 4096  cols (permuted): [q | kv-interleaved | gate]

typedef __attribute__((ext_vector_type(8))) short bf16x8;
typedef __attribute__((ext_vector_type(4))) float f32x4;

__device__ __forceinline__ unsigned short f2bf(float f) {
  unsigned u = __float_as_uint(f);
  u += 0x7FFF + ((u >> 16) & 1);   // RNE
  return (unsigned short)(u >> 16);
}
__device__ __forceinline__ float bf2f(unsigned short h) {
  return __uint_as_float(((unsigned)h) << 16);
}

// ---------------------------------------------------------------- prep: all f32->bf16 converts
// blocks [0,4096): permuted weight rows; blocks [4096,8192): x convert (4 float4/thread).
__global__ __launch_bounds__(256) void k_prep(const float* __restrict__ x,
                                              const float* __restrict__ Wqkv,
                                              const float* __restrict__ Wgate,
                                              unsigned short* __restrict__ xb,
                                              unsigned short* __restrict__ wb) {
  int blk = blockIdx.x;
  if (blk < 4096) {
    int n = blk;
    const float* src;
    if (n < 1024) {
      src = Wqkv + (size_t)n * 1024;
    } else if (n < 3072) {
      int t = (n - 1024) >> 4;
      int d = ((t >> 1) << 4) + (n & 15);
      src = Wqkv + (size_t)(1024 + ((t & 1) << 10) + d) * 1024;
    } else {
      src = Wgate + (size_t)(n - 3072) * 1024;
    }
    unsigned short* o = wb + (size_t)n * 1024;
    int i = threadIdx.x * 4;
    float4 v = *(const float4*)(src + i);
    ushort4 u;
    u.x = f2bf(v.x); u.y = f2bf(v.y); u.z = f2bf(v.z); u.w = f2bf(v.w);
    *(ushort4*)(o + i) = u;
  } else {
    int i0 = (blk - 4096) * 1024 + threadIdx.x;
#pragma unroll
    for (int it = 0; it < 4; ++it) {
      int i = i0 + it * 256;
      float4 v = reinterpret_cast<const float4*>(x)[i];
      ushort4 u;
      u.x = f2bf(v.x); u.y = f2bf(v.y); u.z = f2bf(v.z); u.w = f2bf(v.w);
      reinterpret_cast<ushort4*>(xb)[i] = u;
    }
  }
}

// ---------------------------------------------------------------- 256x256 8-phase GEMM
// BM=BN=256, BK=64, 8 waves (2Mx4N), per-wave 128x64 out. LDS 128KiB, T2 swizzle
// byte^=((row&7)<<4) (verified: bank-conflicts -> 0). XCD mapping: each XCD owns a
// 2-column tn strip (1MB of W resident in its L2); tm iterates within the strip.
// Phase sync: plain s_barrier + compiler fences; backend staggers lgkmcnt per operand.
// Counted vmcnt(4) at dbuf flips only (asm memory fences double as motion barriers).
#define VMW4() asm volatile("s_waitcnt vmcnt(4)" ::: "memory")
#define VMW0() asm volatile("s_waitcnt vmcnt(0)" ::: "memory")
#define FEN() asm volatile("" ::: "memory")

__global__ __launch_bounds__(512, 2) void k_gemm3(const unsigned short* __restrict__ A,
                                                  const unsigned short* __restrict__ W,
                                                  unsigned short* __restrict__ Qd,
                                                  unsigned short* __restrict__ KVd,
                                                  unsigned short* __restrict__ Gd,
                                                  float* __restrict__ part,
                                                  const float* __restrict__ bqkv,
                                                  const float* __restrict__ bgate) {
  __shared__ unsigned short sm[65536];  // 128 KiB

  int bid0 = blockIdx.x;
  int xcd = bid0 & 7;
  int rr = bid0 >> 3;                 // 0..127, dispatch order within XCD
  int tn = xcd * 2 + (rr & 1);        // XCD-resident W strip (2 panels = 1MB)
  int tm = rr >> 1;                   // 0..63
  int m0 = tm * 256, n0 = tn * 256;

  int tid = threadIdx.x, wave = tid >> 6, lane = tid & 63;
  int wm = wave >> 2, wn = wave & 3;
  int r = lane & 15, g = lane >> 4;

  // staging source (per-lane, inverse-swizzled): L = tid*16; swz(L)=L^(((L>>7)&7)<<4)
  int pt = tid * 16;
  int psw = pt ^ (((pt >> 7) & 7) << 4);
  int srow = psw >> 7;
  int scol = (psw & 127) >> 1;
  const unsigned short* Ag = A + (size_t)(m0 + srow) * KK + scol;
  const unsigned short* Wg = W + (size_t)(n0 + srow) * KK + scol;

#define STG_A(kt, h, d) do {                                                              \
    __builtin_amdgcn_global_load_lds(                                                     \
        (const __attribute__((address_space(1))) void*)(Ag + (size_t)(h)*131072 + (kt)*64), \
        (__attribute__((address_space(3))) void*)&sm[(d)*16384 + (h)*8192 + wave*512], 16, 0, 0); \
    __builtin_amdgcn_global_load_lds(                                                     \
        (const __attribute__((address_space(1))) void*)(Ag + (size_t)(h)*131072 + 65536 + (kt)*64), \
        (__attribute__((address_space(3))) void*)&sm[(d)*16384 + (h)*8192 + 4096 + wave*512], 16, 0, 0); \
  } while (0)
#define STG_B(kt, h, d) do {                                                              \
    __builtin_amdgcn_global_load_lds(                                                     \
        (const __attribute__((address_space(1))) void*)(Wg + (size_t)(h)*131072 + (kt)*64), \
        (__attribute__((address_space(3))) void*)&sm[32768 + (d)*16384 + (h)*8192 + wave*512], 16, 0, 0); \
    __builtin_amdgcn_global_load_lds(                                                     \
        (const __attribute__((address_space(1))) void*)(Wg + (size_t)(h)*131072 + 65536 + (kt)*64), \
        (__attribute__((address_space(3))) void*)&sm[32768 + (d)*16384 + (h)*8192 + 4096 + wave*512], 16, 0, 0); \
  } while (0)

  // ds_read (swizzled): ushort addr = region + m*1024 + r*64 + ((ks*32 + g*8) ^ ((r&7)<<3))
  int sx = (r & 7) << 3;
  int aX0 = (r * 64 + g * 8) ^ sx;
  int aX1 = (r * 64 + 32 + g * 8) ^ sx;
  int aReg = wm * 8192;
  int bReg = 32768 + (wn >> 1) * 8192 + (wn & 1) * 4096;

#define LDSA(d, m, ks) (*reinterpret_cast<const bf16x8*>(&sm[aReg + (d)*16384 + (m)*1024 + ((ks) ? aX1 : aX0)]))
#define LDSB(d, n, ks) (*reinterpret_cast<const bf16x8*>(&sm[bReg + (d)*16384 + (n)*1024 + ((ks) ? aX1 : aX0)]))

  f32x4 acc[8][4] = {};
  bf16x8 a[4][2], Bn[4][2];

#define RD_A(d, mb) do { _Pragma("unroll") for (int mi = 0; mi < 4; ++mi) {               \
    _Pragma("unroll") for (int ks = 0; ks < 2; ++ks) { a[mi][ks] = LDSA(d, (mb)+mi, ks); } } } while (0)
#define RD_B(d, nb) do { _Pragma("unroll") for (int ni = 0; ni < 2; ++ni) {               \
    _Pragma("unroll") for (int ks = 0; ks < 2; ++ks) { Bn[(nb)+ni][ks] = LDSB(d, (nb)+ni, ks); } } } while (0)

#define BARW() do { FEN(); __builtin_amdgcn_s_barrier(); FEN(); } while (0)
#define ENDB() do { FEN(); __builtin_amdgcn_s_barrier(); FEN(); } while (0)

#define MFMA16(mb, nb) do {                                                               \
    __builtin_amdgcn_s_setprio(1);                                                        \
    _Pragma("unroll") for (int mi = 0; mi < 4; ++mi) {                                    \
      _Pragma("unroll") for (int ni = 0; ni < 2; ++ni) {                                  \
        _Pragma("unroll") for (int ks = 0; ks < 2; ++ks) {                                \
          acc[(mb)+mi][(nb)+ni] = __builtin_amdgcn_mfma_f32_16x16x32_bf16(                \
              a[mi][ks], Bn[(nb)+ni][ks], acc[(mb)+mi][(nb)+ni], 0, 0, 0);                \
        } } }                                                                             \
    __builtin_amdgcn_s_setprio(0); } while (0)

  // prologue: T0 (dbuf0) + B-T1 (dbuf1)
  STG_A(0, 0, 0); STG_A(0, 1, 0);
  STG_B(0, 0, 0); STG_B(0, 1, 0);
  STG_B(1, 0, 1); STG_B(1, 1, 1);
  VMW4();
  __builtin_amdgcn_s_barrier();
  FEN();

  // main loop: 7 iters x 2 K-tiles (T0..T13); peeled final (T14,T15)
  for (int i = 0; i < 7; ++i) {
    int tb = 2 * i + 1, tc = 2 * i + 2, td = 2 * i + 3;
    RD_A(0, 0); RD_B(0, 0); STG_A(tb, 0, 1);
    BARW(); MFMA16(0, 0); ENDB();
    RD_B(0, 2); STG_A(tb, 1, 1);
    BARW(); MFMA16(0, 2); ENDB();
    RD_A(0, 4); STG_B(tc, 0, 0);
    BARW(); MFMA16(4, 0); ENDB();
    STG_B(tc, 1, 0);
    BARW(); MFMA16(4, 2); VMW4(); ENDB();
    RD_A(1, 0); RD_B(1, 0); STG_A(tc, 0, 0);
    BARW(); MFMA16(0, 0); ENDB();
    RD_B(1, 2); STG_A(tc, 1, 0);
    BARW(); MFMA16(0, 2); ENDB();
    RD_A(1, 4); STG_B(td, 0, 1);
    BARW(); MFMA16(4, 0); ENDB();
    STG_B(td, 1, 1);
    BARW(); MFMA16(4, 2); VMW4(); ENDB();
  }
  RD_A(0, 0); RD_B(0, 0); STG_A(15, 0, 1);
  BARW(); MFMA16(0, 0); ENDB();
  RD_B(0, 2); STG_A(15, 1, 1);
  BARW(); MFMA16(0, 2); ENDB();
  RD_A(0, 4);
  BARW(); MFMA16(4, 0); ENDB();
  BARW(); MFMA16(4, 2); VMW0(); ENDB();
  RD_A(1, 0); RD_B(1, 0);
  BARW(); MFMA16(0, 0); ENDB();
  RD_B(1, 2);
  BARW(); MFMA16(0, 2); ENDB();
  RD_A(1, 4);
  BARW(); MFMA16(4, 0); ENDB();
  BARW(); MFMA16(4, 2);

  // epilogue (C/D layout col=lane&15, row=(lane>>4)*4+q)
  int growb = m0 + wm * 128 + g * 4;
  if (tn < 4) {
#pragma unroll
    for (int n = 0; n < 4; ++n) {
      int col = n0 + wn * 64 + n * 16 + r;
      float bias = bqkv[col];
#pragma unroll
      for (int m = 0; m < 8; ++m)
#pragma unroll
        for (int q = 0; q < 4; ++q)
          Qd[(size_t)(growb + m * 16 + q) * DD + col] = f2bf(acc[m][n][q] + bias);
    }
  } else if (tn < 12) {
    // kv region + fused pass1 chunk partials (chunks of 32 rows)
    int dbase = ((n0 - 1024) >> 1) + (wn * 32);
#pragma unroll
    for (int np = 0; np < 2; ++np) {
      int d = dbase + np * 16 + r;
      float bk = bqkv[1024 + d], bv = bqkv[2048 + d];
      float pairsum = 0.f;
#pragma unroll
      for (int m = 0; m < 8; ++m) {
        float ps = 0.f;
#pragma unroll
        for (int q = 0; q < 4; ++q) {
          float kvv = (acc[m][2 * np][q] + bk) * (acc[m][2 * np + 1][q] + bv);
          KVd[(size_t)(growb + m * 16 + q) * DD + d] = f2bf(kvv);
          ps += kvv;
        }
        ps += __shfl_xor(ps, 16, 64);
        ps += __shfl_xor(ps, 32, 64);
        if ((m & 1) == 0) {
          pairsum = ps;
        } else {
          pairsum += ps;
          if (lane < 16) {
            int cg = tm * 8 + wm * 4 + (m >> 1);  // global chunk id = row/32
            part[(size_t)cg * DD + d] = pairsum;
          }
        }
      }
    }
  } else {
    int cb0 = n0 - 3072;
#pragma unroll
    for (int n = 0; n < 4; ++n) {
      int c = cb0 + wn * 64 + n * 16 + r;
      float bias = bgate[c];
#pragma unroll
      for (int m = 0; m < 8; ++m)
#pragma unroll
        for (int q = 0; q < 4; ++q) {
          float gv = acc[m][n][q] + bias;
          Gd[(size_t)(growb + m * 16 + q) * DD + c] = f2bf(1.f / (1.f + __expf(-gv)));
        }
    }
  }
#undef STG_A
#undef STG_B
#undef LDSA
#undef LDSB
#undef RD_A
#undef RD_B
#undef BARW
#undef ENDB
#undef MFMA16
}

// ---------------------------------------------------------------- final pass
#define NCH 128
#define CSZ (SS / NCH)  // 32

__global__ __launch_bounds__(256) void k_pass3(const unsigned short* __restrict__ Q,
                                               const unsigned short* __restrict__ KV,
                                               const unsigned short* __restrict__ G,
                                               const float* __restrict__ part,
                                               float* __restrict__ out) {
  int b = blockIdx.x >> 7;
  int c = blockIdx.x & (NCH - 1);
  int d = threadIdx.x * 4;
  float4 a = {0.f, 0.f, 0.f, 0.f};
  const float* pb = &part[(size_t)b * NCH * DD + d];
  for (int cc = 0; cc < c; ++cc) {
    float4 p = *(const float4*)(pb + (size_t)cc * DD);
    a.x += p.x; a.y += p.y; a.z += p.z; a.w += p.w;
  }
  for (int s = c * CSZ; s < (c + 1) * CSZ; ++s) {
    size_t rowb = (size_t)(b * SS + s) * DD;
    ushort4 q4 = *(const ushort4*)&Q[rowb + d];
    ushort4 kv4 = *(const ushort4*)&KV[rowb + d];
    ushort4 g4 = *(const ushort4*)&G[rowb + d];
    a.x += bf2f(kv4.x); a.y += bf2f(kv4.y); a.z += bf2f(kv4.z); a.w += bf2f(kv4.w);
    float4 o;
    o.x = bf2f(q4.x) * a.x * bf2f(g4.x);
    o.y = bf2f(q4.y) * a.y * bf2f(g4.y);
    o.z = bf2f(q4.z) * a.z * bf2f(g4.z);
    o.w = bf2f(q4.w) * a.w * bf2f(g4.w);
    *(float4*)&out[rowb + d] = o;
  }
}

// ---------------------------------------------------------------- launch
extern "C" void kernel_launch(void* const* d_in, const int* in_sizes, int n_in,
                              void* d_out, int out_size, void* d_ws, size_t ws_size,
                              hipStream_t stream) {
  const float* x = (const float*)d_in[0];
  const float* Wqkv = (const float*)d_in[1];
  const float* bqkv = (const float*)d_in[2];
  const float* Wgate = (const float*)d_in[3];
  const float* bgate = (const float*)d_in[4];
  float* out = (float*)d_out;

  char* ws = (char*)d_ws;
  unsigned short* xb = (unsigned short*)ws;                        // 32 MB bf16 x
  unsigned short* wb = (unsigned short*)(ws + (size_t)33554432);   // 8 MB  bf16 permuted W
  unsigned short* Qd = (unsigned short*)(ws + (size_t)41943040);   // 32 MB
  unsigned short* KVd = (unsigned short*)(ws + (size_t)75497472);  // 32 MB
  unsigned short* Gd = (unsigned short*)(ws + (size_t)109051904);  // 32 MB
  float* part = (float*)(ws + (size_t)142606336);                  // 2 MB [512 chunks][1024]

  k_prep<<<8192, 256, 0, stream>>>(x, Wqkv, Wgate, xb, wb);
  k_gemm3<<<1024, 512, 0, stream>>>(xb, wb, Qd, KVd, Gd, part, bqkv, bgate);
  k_pass3<<<BB * NCH, 256, 0, stream>>>(Qd, KVd, Gd, part, out);
}